// Round 12
// baseline (145.597 us; speedup 1.0000x reference)
//
#include <hip/hip_runtime.h>
#include <math.h>

// Performer (FAVOR+) causal attention. B=1, L=2048, D=512, H=8, DH=64, M=128.
// Round 12: COALESCED GEMM staging. R11's loads mapped lane->row (2KB lane
// stride, 64 scattered 32B transactions per instruction — the real qkvp
// bottleneck). Now lane->K (row=t>>3,k8=t&7): contiguous 256B per 8 lanes.

#define L       2048
#define DMODEL  512
#define NH      8
#define DH      64
#define M       128
#define CT      64          // chunk size
#define NC      (L/CT)      // 32 chunks per head
#define KEPS    1e-4f
#define DEPS    1e-6f
#define SCALE   0.2102241038134286f   // 512^-0.25
#define NCONST  0.08838834764831845f  // 128^-0.5

// workspace layout (float offsets). total = 4227072 floats = 16.9 MB
#define OFF_VB     0          // bf16 [l][512]
#define OFF_QPB    524288     // bf16 [h][l][m]
#define OFF_KPB    1572864
#define OFF_SSB    2621440    // bf16 [h][c][m*64+d]  (S), prefix in-place
#define OFF_SSZ    3670016    // fp32 [h][c][m]       (z), prefix in-place
#define OFF_CTX    3702784    // bf16 [l][512]
#define OFF_END    4227072

typedef short bf16x8 __attribute__((ext_vector_type(8)));
typedef float f32x4  __attribute__((ext_vector_type(4)));
typedef unsigned short ushort_t;

__device__ __forceinline__ ushort_t f2bf(float f) {
    unsigned u = __float_as_uint(f);
    return (ushort_t)((u + 0x7fffu + ((u >> 16) & 1u)) >> 16);
}
__device__ __forceinline__ float bf2f(ushort_t u) {
    return __uint_as_float(((unsigned)u) << 16);
}
__device__ __forceinline__ unsigned pack2(float a, float b) {
    return (unsigned)f2bf(a) | ((unsigned)f2bf(b) << 16);
}

// ---- fused QKV projection + (for Q,K) feature map --------------------------
// grid (32, 4, 3), 256 thr; 64-row tiles, K-chunk 64 (8 iters), coalesced.
__global__ __launch_bounds__(256) void qkvp_kernel(
    const float* __restrict__ xq, const float* __restrict__ xk, const float* __restrict__ xv,
    const float* __restrict__ Wq, const float* __restrict__ bq,
    const float* __restrict__ Wk, const float* __restrict__ bk,
    const float* __restrict__ Wv, const float* __restrict__ bv,
    const float* __restrict__ RF,
    ushort_t* __restrict__ Vb, ushort_t* __restrict__ QPb, ushort_t* __restrict__ KPb)
{
    __shared__ __align__(16) char smem[24576];      // As8[8*64]=8KB | Bs8[8*128]=16KB ; aliased by RFTs
    __shared__ ushort_t Qt[64 * 136];               // 17.4 KB gemm tile (2 heads)
    __shared__ float ssq[128];
    uint4* As8 = (uint4*)smem;
    uint4* Bs8 = (uint4*)(smem + 8192);
    ushort_t* RFTs = (ushort_t*)smem;               // [m][72] used after gemm

    const int tid  = threadIdx.x;
    const int lane = tid & 63;
    const int wave = tid >> 6;
    const int quad = lane >> 4;
    const int l15  = lane & 15;
    const int z = blockIdx.z;
    const int isK = (z == 1);
    const int row0 = blockIdx.x * 64;
    const int col0 = blockIdx.y * 128;

    const float* X; const float* W; const float* bias;
    if (z == 0)      { X = xq; W = Wq; bias = bq; }
    else if (z == 1) { X = xk; W = Wk; bias = bk; }
    else             { X = xv; W = Wv; bias = bv; }

    // ---- GEMM, K-chunk 64, coalesced task map: row=t>>3, k8=t&7 ----
    f32x4 acc[4][2];
    const f32x4 z4 = {0.f, 0.f, 0.f, 0.f};
    #pragma unroll
    for (int i = 0; i < 4; ++i) { acc[i][0] = z4; acc[i][1] = z4; }

    uint4 ra[2], rb[4];
    auto loadA = [&](int ck) {
        #pragma unroll
        for (int it = 0; it < 2; ++it) {
            int t = tid + it * 256;
            int row = t >> 3, k8 = t & 7;
            const float4* gp = (const float4*)&X[(row0 + row) * DMODEL + ck * 64 + k8 * 8];
            float4 v0 = gp[0], v1 = gp[1];
            ra[it] = make_uint4(pack2(v0.x, v0.y), pack2(v0.z, v0.w),
                                pack2(v1.x, v1.y), pack2(v1.z, v1.w));
        }
    };
    auto loadB = [&](int ck) {
        #pragma unroll
        for (int it = 0; it < 4; ++it) {
            int t = tid + it * 256;
            int col = t >> 3, k8 = t & 7;
            const float4* gp = (const float4*)&W[(col0 + col) * DMODEL + ck * 64 + k8 * 8];
            float4 v0 = gp[0], v1 = gp[1];
            rb[it] = make_uint4(pack2(v0.x, v0.y), pack2(v0.z, v0.w),
                                pack2(v1.x, v1.y), pack2(v1.z, v1.w));
        }
    };

    loadA(0); loadB(0);
    const int wn = wave;
    for (int ck = 0; ck < 8; ++ck) {
        __syncthreads();
        #pragma unroll
        for (int it = 0; it < 2; ++it) {
            int t = tid + it * 256;
            As8[(t & 7) * 64 + (t >> 3)] = ra[it];
        }
        #pragma unroll
        for (int it = 0; it < 4; ++it) {
            int t = tid + it * 256;
            Bs8[(t & 7) * 128 + (t >> 3)] = rb[it];
        }
        __syncthreads();
        if (ck < 7) { loadA(ck + 1); loadB(ck + 1); }
        const bf16x8* Av = (const bf16x8*)As8;
        const bf16x8* Bv = (const bf16x8*)Bs8;
        #pragma unroll
        for (int kc = 0; kc < 2; ++kc) {
            const int k8 = kc * 4 + quad;
            bf16x8 af[4], bfr[2];
            #pragma unroll
            for (int i = 0; i < 4; ++i) af[i] = Av[k8 * 64 + i * 16 + l15];
            #pragma unroll
            for (int j = 0; j < 2; ++j) bfr[j] = Bv[k8 * 128 + wn * 32 + j * 16 + l15];
            #pragma unroll
            for (int i = 0; i < 4; ++i)
                #pragma unroll
                for (int j = 0; j < 2; ++j)
                    acc[i][j] = __builtin_amdgcn_mfma_f32_16x16x32_bf16(af[i], bfr[j], acc[i][j], 0, 0, 0);
        }
    }

    if (z == 2) {   // V epilogue -> global bf16
        #pragma unroll
        for (int i = 0; i < 4; ++i)
            #pragma unroll
            for (int j = 0; j < 2; ++j) {
                int c = col0 + wn * 32 + j * 16 + l15;
                float bv_ = bias[c];
                #pragma unroll
                for (int reg = 0; reg < 4; ++reg) {
                    int r = row0 + i * 16 + quad * 4 + reg;
                    Vb[r * DMODEL + c] = f2bf(acc[i][j][reg] + bv_);
                }
            }
        return;
    }

    // ---- Q/K epilogue -> LDS tile ----
    #pragma unroll
    for (int i = 0; i < 4; ++i)
        #pragma unroll
        for (int j = 0; j < 2; ++j) {
            int c = wn * 32 + j * 16 + l15;                  // 0..127 (2 heads)
            float bv_ = bias[col0 + c];
            #pragma unroll
            for (int reg = 0; reg < 4; ++reg) {
                int r = i * 16 + quad * 4 + reg;             // 0..63
                Qt[r * 136 + c] = f2bf(acc[i][j][reg] + bv_);
            }
        }
    __syncthreads();     // all As8/Bs8 reads done; safe to alias with RFTs

    {   // stage RF -> RFTs[m][d] bf16 with SCALE folded (coalesced in m)
        int m = tid & 127, half = tid >> 7;
        #pragma unroll
        for (int j = 0; j < 32; ++j) {
            int d = half * 32 + j;
            RFTs[m * 72 + d] = f2bf(SCALE * RF[d * M + m]);
        }
    }
    if (isK && tid < 128) {      // per (head-half, row) sumsq
        int hh = tid >> 6, row = tid & 63;
        float s = 0.f;
        #pragma unroll
        for (int d = 0; d < DH; ++d) {
            float v = bf2f(Qt[row * 136 + hh * 64 + d]);
            s += v * v;
        }
        ssq[tid] = s;
    }
    __syncthreads();

    // ---- primes MFMA: per wave (head-half hh, m-half mh), 64 rows x 64 m ----
    const int hh = wave >> 1, mh = wave & 1;
    const float s2h = 0.5f * SCALE * SCALE;
    f32x4 pac[4][4];
    #pragma unroll
    for (int i = 0; i < 4; ++i)
        #pragma unroll
        for (int j = 0; j < 4; ++j) pac[i][j] = z4;
    #pragma unroll
    for (int kc = 0; kc < 2; ++kc) {
        bf16x8 af[4], bfr[4];
        #pragma unroll
        for (int i = 0; i < 4; ++i)
            af[i] = *(const bf16x8*)&Qt[(i * 16 + l15) * 136 + hh * 64 + kc * 32 + quad * 8];
        #pragma unroll
        for (int j = 0; j < 4; ++j)
            bfr[j] = *(const bf16x8*)&RFTs[(mh * 64 + j * 16 + l15) * 72 + kc * 32 + quad * 8];
        #pragma unroll
        for (int i = 0; i < 4; ++i)
            #pragma unroll
            for (int j = 0; j < 4; ++j)
                pac[i][j] = __builtin_amdgcn_mfma_f32_16x16x32_bf16(af[i], bfr[j], pac[i][j], 0, 0, 0);
    }

    ushort_t* dst = isK ? KPb : QPb;
    const int hgl = blockIdx.y * 2 + hh;
    #pragma unroll
    for (int i = 0; i < 4; ++i)
        #pragma unroll
        for (int reg = 0; reg < 4; ++reg) {
            int row = i * 16 + quad * 4 + reg;
            float off = isK ? (-s2h * ssq[hh * 64 + row]) : 0.f;
            #pragma unroll
            for (int j = 0; j < 4; ++j) {
                int m = mh * 64 + j * 16 + l15;
                float p = pac[i][j][reg] + off;
                dst[((long)hgl * L + row0 + row) * M + m] = f2bf(NCONST * (expf(p) + KEPS));
            }
        }
}

// ---------------- output GEMM (bf16 A, fp32 W inline-cast), K-chunk 64 ------
__global__ __launch_bounds__(256) void out_gemm_kernel(
    const ushort_t* __restrict__ ctxb, const float* __restrict__ Wo,
    const float* __restrict__ bo, float* __restrict__ out)
{
    __shared__ uint4 As8[8 * 32];    // 4 KB
    __shared__ uint4 Bs8[8 * 128];   // 16 KB
    const int tid  = threadIdx.x;
    const int lane = tid & 63;
    const int wn   = tid >> 6;
    const int quad = lane >> 4;
    const int l15  = lane & 15;
    const int row0 = blockIdx.x * 32;
    const int col0 = blockIdx.y * 128;

    f32x4 acc[2][2];
    const f32x4 z4 = {0.f, 0.f, 0.f, 0.f};
    acc[0][0] = z4; acc[0][1] = z4; acc[1][0] = z4; acc[1][1] = z4;

    uint4 ra, rb[4];
    auto loadA = [&](int ck) {
        int row = tid >> 3, k8 = tid & 7;    // coalesced: 8 lanes per 128B row chunk
        ra = *(const uint4*)&ctxb[(row0 + row) * DMODEL + ck * 64 + k8 * 8];
    };
    auto loadB = [&](int ck) {
        #pragma unroll
        for (int it = 0; it < 4; ++it) {
            int t = tid + it * 256;
            int col = t >> 3, k8 = t & 7;
            const float4* gp = (const float4*)&Wo[(col0 + col) * DMODEL + ck * 64 + k8 * 8];
            float4 v0 = gp[0], v1 = gp[1];
            rb[it] = make_uint4(pack2(v0.x, v0.y), pack2(v0.z, v0.w),
                                pack2(v1.x, v1.y), pack2(v1.z, v1.w));
        }
    };

    loadA(0); loadB(0);
    for (int ck = 0; ck < 8; ++ck) {
        __syncthreads();
        As8[(tid & 7) * 32 + (tid >> 3)] = ra;
        #pragma unroll
        for (int it = 0; it < 4; ++it) {
            int t = tid + it * 256;
            Bs8[(t & 7) * 128 + (t >> 3)] = rb[it];
        }
        __syncthreads();
        if (ck < 7) { loadA(ck + 1); loadB(ck + 1); }
        const bf16x8* Av = (const bf16x8*)As8;
        const bf16x8* Bv = (const bf16x8*)Bs8;
        #pragma unroll
        for (int kc = 0; kc < 2; ++kc) {
            const int k8 = kc * 4 + quad;
            bf16x8 af[2], bfr[2];
            af[0] = Av[k8 * 32 + l15];
            af[1] = Av[k8 * 32 + 16 + l15];
            #pragma unroll
            for (int j = 0; j < 2; ++j) bfr[j] = Bv[k8 * 128 + wn * 32 + j * 16 + l15];
            #pragma unroll
            for (int i = 0; i < 2; ++i)
                #pragma unroll
                for (int j = 0; j < 2; ++j)
                    acc[i][j] = __builtin_amdgcn_mfma_f32_16x16x32_bf16(af[i], bfr[j], acc[i][j], 0, 0, 0);
        }
    }
    #pragma unroll
    for (int i = 0; i < 2; ++i)
        #pragma unroll
        for (int j = 0; j < 2; ++j) {
            int c = col0 + wn * 32 + j * 16 + l15;
            float bv_ = bo[c];
            #pragma unroll
            for (int reg = 0; reg < 4; ++reg) {
                int r = row0 + i * 16 + quad * 4 + reg;
                out[r * DMODEL + c] = acc[i][j][reg] + bv_;
            }
        }
}

// ------- chunk sums via MFMA: S[m][d] = K'^T V, z[m] via ones-row -----------
__global__ __launch_bounds__(256) void chunksum_mfma_kernel(
    const ushort_t* __restrict__ KPb, const ushort_t* __restrict__ Vb,
    ushort_t* __restrict__ SSb, float* __restrict__ SSz)
{
    __shared__ ushort_t Kt[128 * 72];   // K'^T [m][t]
    __shared__ ushort_t Vt[80 * 72];    // V^T [d][t]; row 64 = ones; 65..79 zero
    const int tid = threadIdx.x;
    const int c = blockIdx.x, h = blockIdx.y;
    const int lane = tid & 63;
    const int wave = tid >> 6;
    const int quad = lane >> 4, l15 = lane & 15;
    const int t = lane, g = wave;

    {   // transpose-stage K' (64x128) and V (64x64); lanes along t -> conflict-free
        const ushort_t* kr = &KPb[((long)(h * L) + c * CT + t) * M];
        #pragma unroll
        for (int it = 0; it < 4; ++it) {
            int mo = it * 4 + g;
            uint4 u = *(const uint4*)&kr[mo * 8];
            ushort_t e[8] = {(ushort_t)(u.x & 0xffff), (ushort_t)(u.x >> 16),
                             (ushort_t)(u.y & 0xffff), (ushort_t)(u.y >> 16),
                             (ushort_t)(u.z & 0xffff), (ushort_t)(u.z >> 16),
                             (ushort_t)(u.w & 0xffff), (ushort_t)(u.w >> 16)};
            #pragma unroll
            for (int j = 0; j < 8; ++j) Kt[(mo * 8 + j) * 72 + t] = e[j];
        }
        const ushort_t* vr = &Vb[(c * CT + t) * DMODEL + h * DH];
        #pragma unroll
        for (int it = 0; it < 2; ++it) {
            int dd = it * 4 + g;
            uint4 u = *(const uint4*)&vr[dd * 8];
            ushort_t e[8] = {(ushort_t)(u.x & 0xffff), (ushort_t)(u.x >> 16),
                             (ushort_t)(u.y & 0xffff), (ushort_t)(u.y >> 16),
                             (ushort_t)(u.z & 0xffff), (ushort_t)(u.z >> 16),
                             (ushort_t)(u.w & 0xffff), (ushort_t)(u.w >> 16)};
            #pragma unroll
            for (int j = 0; j < 8; ++j) Vt[(dd * 8 + j) * 72 + t] = e[j];
        }
        if (g == 0) Vt[64 * 72 + t] = 0x3F80;     // bf16 1.0
        if (g == 1) {
            #pragma unroll
            for (int r = 65; r < 80; ++r) Vt[r * 72 + t] = 0;
        }
    }
    __syncthreads();

    f32x4 acc[2][5];
    const f32x4 z4 = {0.f, 0.f, 0.f, 0.f};
    #pragma unroll
    for (int i = 0; i < 2; ++i)
        #pragma unroll
        for (int j = 0; j < 5; ++j) acc[i][j] = z4;
    #pragma unroll
    for (int kt = 0; kt < 2; ++kt) {
        bf16x8 af[2], bfr[5];
        #pragma unroll
        for (int i = 0; i < 2; ++i)
            af[i] = *(const bf16x8*)&Kt[(wave * 32 + i * 16 + l15) * 72 + kt * 32 + quad * 8];
        #pragma unroll
        for (int j = 0; j < 5; ++j)
            bfr[j] = *(const bf16x8*)&Vt[(j * 16 + l15) * 72 + kt * 32 + quad * 8];
        #pragma unroll
        for (int i = 0; i < 2; ++i)
            #pragma unroll
            for (int j = 0; j < 5; ++j)
                acc[i][j] = __builtin_amdgcn_mfma_f32_16x16x32_bf16(af[i], bfr[j], acc[i][j], 0, 0, 0);
    }
    ushort_t* outS = SSb + (long)(h * NC + c) * 8192;
    #pragma unroll
    for (int i = 0; i < 2; ++i)
        #pragma unroll
        for (int reg = 0; reg < 4; ++reg) {
            int m = wave * 32 + i * 16 + quad * 4 + reg;
            #pragma unroll
            for (int j = 0; j < 4; ++j)
                outS[m * 64 + j * 16 + l15] = f2bf(acc[i][j][reg]);
            if (l15 == 0) SSz[(h * NC + c) * M + m] = acc[i][4][reg];
        }
}

// ------- in-place exclusive prefix over chunks (batched loads) --------------
__global__ __launch_bounds__(256) void prefix_kernel(
    ushort_t* __restrict__ SSb, float* __restrict__ SSz)
{
    const int h = blockIdx.y;
    if (blockIdx.x == 32) {
        const int m = threadIdx.x;
        if (m < M) {
            float v[NC];
            #pragma unroll
            for (int c = 0; c < NC; ++c) v[c] = SSz[(h * NC + c) * M + m];
            float run = 0.f;
            #pragma unroll
            for (int c = 0; c < NC; ++c) {
                SSz[(h * NC + c) * M + m] = run;
                run += v[c];
            }
        }
        return;
    }
    const int idx = blockIdx.x * 256 + threadIdx.x;   // < 8192
    ushort_t v[NC];
    #pragma unroll
    for (int c = 0; c < NC; ++c) v[c] = SSb[(long)(h * NC + c) * 8192 + idx];
    float run = 0.f;
    #pragma unroll
    for (int c = 0; c < NC; ++c) {
        SSb[(long)(h * NC + c) * 8192 + idx] = f2bf(run);
        run += bf2f(v[c]);
    }
}

// ---------------- per-chunk causal kernel attention (MFMA) ------------------
// den = [Am|Q'] @ [ones;z] = output column 64 of the phase-2 MFMA.
__global__ __launch_bounds__(512) void attn_kernel(
    const ushort_t* __restrict__ QPb, const ushort_t* __restrict__ KPb,
    const ushort_t* __restrict__ Vb, const ushort_t* __restrict__ SSb,
    const float* __restrict__ SSz, ushort_t* __restrict__ ctxb)
{
    __shared__ ushort_t Qp[64 * 136];   // stride 136 bf16
    __shared__ ushort_t Kp[64 * 136];
    __shared__ ushort_t St[80 * 136];   // S^T [d][m]; row 64 = z
    __shared__ ushort_t Vt[80 * 72];    // V^T [d][t]; row 64 = ones
    __shared__ ushort_t Am[64 * 72];    // masked scores [row][col]
    __shared__ float den[CT];
    const int tid = threadIdx.x;
    const int c = blockIdx.x, h = blockIdx.y;
    const int lane = tid & 63;
    const int wave = tid >> 6;
    const int i  = wave & 3;            // rows tile (16 rows)
    const int nh = wave >> 2;           // cols half (32 cols)
    const int quad = lane >> 4;
    const int l15  = lane & 15;

    // ---- stage ----
    for (int t = tid; t < 2048; t += 512) {          // Qp/Kp
        int mat = t >> 10, r = (t >> 4) & 63, c8 = t & 15;
        const ushort_t* src = mat ? KPb : QPb;
        uint4 u = *(const uint4*)&src[((long)(h * L) + c * CT + r) * M + c8 * 8];
        ushort_t* dst = mat ? Kp : Qp;
        *(uint4*)&dst[r * 136 + c8 * 8] = u;
    }
    {   // Vt: transpose V 64x64 bf16
        int t = tid & 63, dg = tid >> 6;
        uint4 u = *(const uint4*)&Vb[(c * CT + t) * DMODEL + h * DH + dg * 8];
        ushort_t e[8] = {(ushort_t)(u.x & 0xffff), (ushort_t)(u.x >> 16),
                         (ushort_t)(u.y & 0xffff), (ushort_t)(u.y >> 16),
                         (ushort_t)(u.z & 0xffff), (ushort_t)(u.z >> 16),
                         (ushort_t)(u.w & 0xffff), (ushort_t)(u.w >> 16)};
        #pragma unroll
        for (int j = 0; j < 8; ++j) Vt[(dg * 8 + j) * 72 + t] = e[j];
    }
    {   // St[d][m] from S[m][d] (transpose-scatter, lanes along m -> free)
        const ushort_t* ssb = SSb + (long)(h * NC + c) * 8192;
        int m = tid & 127, dg = tid >> 7;    // dg 0..3
        #pragma unroll
        for (int it = 0; it < 2; ++it) {
            int dd = it * 4 + dg;            // d-octet 0..7
            uint4 u = *(const uint4*)&ssb[m * 64 + dd * 8];
            ushort_t e[8] = {(ushort_t)(u.x & 0xffff), (ushort_t)(u.x >> 16),
                             (ushort_t)(u.y & 0xffff), (ushort_t)(u.y >> 16),
                             (ushort_t)(u.z & 0xffff), (ushort_t)(u.z >> 16),
                             (ushort_t)(u.w & 0xffff), (ushort_t)(u.w >> 16)};
            #pragma unroll
            for (int j = 0; j < 8; ++j) St[(dd * 8 + j) * 136 + m] = e[j];
        }
    }
    if (tid < 128) St[64 * 136 + tid] = f2bf(SSz[(h * NC + c) * M + tid]);  // z row
    if (tid >= 128 && tid < 192) Vt[64 * 72 + (tid - 128)] = 0x3F80;        // ones
    for (int t = tid; t < 15 * 136; t += 512) St[65 * 136 + t] = 0;         // pad
    for (int t = tid; t < 15 * 72; t += 512)  Vt[65 * 72 + t] = 0;
    __syncthreads();

    // ---- phase 1: scores ----
    f32x4 acc1[2];
    const f32x4 z4 = {0.f, 0.f, 0.f, 0.f};
    acc1[0] = z4; acc1[1] = z4;
    #pragma unroll
    for (int kt = 0; kt < 4; ++kt) {
        bf16x8 af = *(const bf16x8*)&Qp[(i * 16 + l15) * 136 + kt * 32 + quad * 8];
        #pragma unroll
        for (int jt = 0; jt < 2; ++jt) {
            bf16x8 bf = *(const bf16x8*)&Kp[(nh * 32 + jt * 16 + l15) * 136 + kt * 32 + quad * 8];
            acc1[jt] = __builtin_amdgcn_mfma_f32_16x16x32_bf16(af, bf, acc1[jt], 0, 0, 0);
        }
    }
    #pragma unroll
    for (int jt = 0; jt < 2; ++jt) {
        int col = nh * 32 + jt * 16 + l15;
        #pragma unroll
        for (int reg = 0; reg < 4; ++reg) {
            int row = i * 16 + quad * 4 + reg;
            Am[row * 72 + col] = f2bf((col <= row) ? acc1[jt][reg] : 0.f);
        }
    }
    __syncthreads();

    // ---- phase 2: N = [Am|Q'] @ [V;S], den = column 64 ----
    f32x4 acc2[2], acc3;
    acc2[0] = z4; acc2[1] = z4; acc3 = z4;
    #pragma unroll
    for (int kt = 0; kt < 6; ++kt) {
        bf16x8 af = (kt < 2)
            ? *(const bf16x8*)&Am[(i * 16 + l15) * 72 + kt * 32 + quad * 8]
            : *(const bf16x8*)&Qp[(i * 16 + l15) * 136 + (kt - 2) * 32 + quad * 8];
        #pragma unroll
        for (int jt = 0; jt < 2; ++jt) {
            int n = nh * 32 + jt * 16 + l15;
            bf16x8 bf = (kt < 2)
                ? *(const bf16x8*)&Vt[n * 72 + kt * 32 + quad * 8]
                : *(const bf16x8*)&St[n * 136 + (kt - 2) * 32 + quad * 8];
            acc2[jt] = __builtin_amdgcn_mfma_f32_16x16x32_bf16(af, bf, acc2[jt], 0, 0, 0);
        }
        if (nh == 0) {
            bf16x8 bz = (kt < 2)
                ? *(const bf16x8*)&Vt[(64 + l15) * 72 + kt * 32 + quad * 8]
                : *(const bf16x8*)&St[(64 + l15) * 136 + (kt - 2) * 32 + quad * 8];
            acc3 = __builtin_amdgcn_mfma_f32_16x16x32_bf16(af, bz, acc3, 0, 0, 0);
        }
    }
    if (nh == 0 && l15 == 0) {
        #pragma unroll
        for (int reg = 0; reg < 4; ++reg)
            den[i * 16 + quad * 4 + reg] = acc3[reg];
    }
    __syncthreads();
    #pragma unroll
    for (int jt = 0; jt < 2; ++jt) {
        int d = nh * 32 + jt * 16 + l15;
        #pragma unroll
        for (int reg = 0; reg < 4; ++reg) {
            int row = i * 16 + quad * 4 + reg;
            ctxb[(c * CT + row) * DMODEL + h * DH + d] = f2bf(acc2[jt][reg] / (den[row] + DEPS));
        }
    }
}

extern "C" void kernel_launch(void* const* d_in, const int* in_sizes, int n_in,
                              void* d_out, int out_size, void* d_ws, size_t ws_size,
                              hipStream_t stream)
{
    const float* query = (const float*)d_in[0];
    const float* key_  = (const float*)d_in[1];
    const float* value = (const float*)d_in[2];
    const float* Wq = (const float*)d_in[3];
    const float* bq = (const float*)d_in[4];
    const float* Wk = (const float*)d_in[5];
    const float* bk = (const float*)d_in[6];
    const float* Wv = (const float*)d_in[7];
    const float* bv = (const float*)d_in[8];
    const float* Wo = (const float*)d_in[9];
    const float* bo = (const float*)d_in[10];
    const float* RF = (const float*)d_in[11];

    float* ws = (float*)d_ws;
    ushort_t* Vb   = (ushort_t*)(ws + OFF_VB);
    ushort_t* QPb  = (ushort_t*)(ws + OFF_QPB);
    ushort_t* KPb  = (ushort_t*)(ws + OFF_KPB);
    ushort_t* SSb  = (ushort_t*)(ws + OFF_SSB);
    float* SSz     = ws + OFF_SSZ;
    ushort_t* CTXB = (ushort_t*)(ws + OFF_CTX);

    qkvp_kernel<<<dim3(32, 4, 3), 256, 0, stream>>>(query, key_, value,
                                                    Wq, bq, Wk, bk, Wv, bv, RF,
                                                    Vb, QPb, KPb);
    chunksum_mfma_kernel<<<dim3(NC, 8), 256, 0, stream>>>(KPb, Vb, SSb, SSz);
    prefix_kernel<<<dim3(33, 8), 256, 0, stream>>>(SSb, SSz);
    attn_kernel<<<dim3(NC, 8), 512, 0, stream>>>(QPb, KPb, Vb, SSb, SSz, CTXB);
    out_gemm_kernel<<<dim3(64, 4), 256, 0, stream>>>(CTXB, Wo, bo, (float*)d_out);
}

// Round 13
// 138.169 us; speedup vs baseline: 1.0538x; 1.0538x over previous
//
#include <hip/hip_runtime.h>
#include <math.h>

// Performer (FAVOR+) causal attention. B=1, L=2048, D=512, H=8, DH=64, M=128.
// Round 13: R12's coalesced global loads + PADDED LDS stores. R12's K-major
// store map had bank=(row*4)%32 (k8 dropped out) -> 8-way store conflicts.
// Pad k8-row stride by +1 uint4: bank=(4*k8+4*row)%32 -> <=2-way (free).

#define L       2048
#define DMODEL  512
#define NH      8
#define DH      64
#define M       128
#define CT      64          // chunk size
#define NC      (L/CT)      // 32 chunks per head
#define KEPS    1e-4f
#define DEPS    1e-6f
#define SCALE   0.2102241038134286f   // 512^-0.25
#define NCONST  0.08838834764831845f  // 128^-0.5

// workspace layout (float offsets). total = 4227072 floats = 16.9 MB
#define OFF_VB     0          // bf16 [l][512]
#define OFF_QPB    524288     // bf16 [h][l][m]
#define OFF_KPB    1572864
#define OFF_SSB    2621440    // bf16 [h][c][m*64+d]  (S), prefix in-place
#define OFF_SSZ    3670016    // fp32 [h][c][m]       (z), prefix in-place
#define OFF_CTX    3702784    // bf16 [l][512]
#define OFF_END    4227072

typedef short bf16x8 __attribute__((ext_vector_type(8)));
typedef float f32x4  __attribute__((ext_vector_type(4)));
typedef unsigned short ushort_t;

__device__ __forceinline__ ushort_t f2bf(float f) {
    unsigned u = __float_as_uint(f);
    return (ushort_t)((u + 0x7fffu + ((u >> 16) & 1u)) >> 16);
}
__device__ __forceinline__ float bf2f(ushort_t u) {
    return __uint_as_float(((unsigned)u) << 16);
}
__device__ __forceinline__ unsigned pack2(float a, float b) {
    return (unsigned)f2bf(a) | ((unsigned)f2bf(b) << 16);
}

// ---- fused QKV projection + (for Q,K) feature map --------------------------
// grid (32, 4, 3), 256 thr; 64-row tiles, K-chunk 64 (8 iters), coalesced,
// padded LDS (As stride 65, Bs stride 129 uint4).
__global__ __launch_bounds__(256) void qkvp_kernel(
    const float* __restrict__ xq, const float* __restrict__ xk, const float* __restrict__ xv,
    const float* __restrict__ Wq, const float* __restrict__ bq,
    const float* __restrict__ Wk, const float* __restrict__ bk,
    const float* __restrict__ Wv, const float* __restrict__ bv,
    const float* __restrict__ RF,
    ushort_t* __restrict__ Vb, ushort_t* __restrict__ QPb, ushort_t* __restrict__ KPb)
{
    __shared__ __align__(16) char smem[24832];      // As8 8*65 + Bs8 8*129 uint4; aliased by RFTs
    __shared__ ushort_t Qt[64 * 136];               // 17.4 KB gemm tile (2 heads)
    __shared__ float ssq[128];
    uint4* As8 = (uint4*)smem;                      // [k8][row] stride 65
    uint4* Bs8 = (uint4*)(smem + 520 * 16);         // [k8][col] stride 129
    ushort_t* RFTs = (ushort_t*)smem;               // [m][72] used after gemm

    const int tid  = threadIdx.x;
    const int lane = tid & 63;
    const int wave = tid >> 6;
    const int quad = lane >> 4;
    const int l15  = lane & 15;
    const int z = blockIdx.z;
    const int isK = (z == 1);
    const int row0 = blockIdx.x * 64;
    const int col0 = blockIdx.y * 128;

    const float* X; const float* W; const float* bias;
    if (z == 0)      { X = xq; W = Wq; bias = bq; }
    else if (z == 1) { X = xk; W = Wk; bias = bk; }
    else             { X = xv; W = Wv; bias = bv; }

    // ---- GEMM, K-chunk 64, coalesced task map: row=t>>3, k8=t&7 ----
    f32x4 acc[4][2];
    const f32x4 z4 = {0.f, 0.f, 0.f, 0.f};
    #pragma unroll
    for (int i = 0; i < 4; ++i) { acc[i][0] = z4; acc[i][1] = z4; }

    uint4 ra[2], rb[4];
    auto loadA = [&](int ck) {
        #pragma unroll
        for (int it = 0; it < 2; ++it) {
            int t = tid + it * 256;
            int row = t >> 3, k8 = t & 7;
            const float4* gp = (const float4*)&X[(row0 + row) * DMODEL + ck * 64 + k8 * 8];
            float4 v0 = gp[0], v1 = gp[1];
            ra[it] = make_uint4(pack2(v0.x, v0.y), pack2(v0.z, v0.w),
                                pack2(v1.x, v1.y), pack2(v1.z, v1.w));
        }
    };
    auto loadB = [&](int ck) {
        #pragma unroll
        for (int it = 0; it < 4; ++it) {
            int t = tid + it * 256;
            int col = t >> 3, k8 = t & 7;
            const float4* gp = (const float4*)&W[(col0 + col) * DMODEL + ck * 64 + k8 * 8];
            float4 v0 = gp[0], v1 = gp[1];
            rb[it] = make_uint4(pack2(v0.x, v0.y), pack2(v0.z, v0.w),
                                pack2(v1.x, v1.y), pack2(v1.z, v1.w));
        }
    };

    loadA(0); loadB(0);
    const int wn = wave;
    for (int ck = 0; ck < 8; ++ck) {
        __syncthreads();
        #pragma unroll
        for (int it = 0; it < 2; ++it) {
            int t = tid + it * 256;
            As8[(t & 7) * 65 + (t >> 3)] = ra[it];
        }
        #pragma unroll
        for (int it = 0; it < 4; ++it) {
            int t = tid + it * 256;
            Bs8[(t & 7) * 129 + (t >> 3)] = rb[it];
        }
        __syncthreads();
        if (ck < 7) { loadA(ck + 1); loadB(ck + 1); }
        const bf16x8* Av = (const bf16x8*)As8;
        const bf16x8* Bv = (const bf16x8*)Bs8;
        #pragma unroll
        for (int kc = 0; kc < 2; ++kc) {
            const int k8 = kc * 4 + quad;
            bf16x8 af[4], bfr[2];
            #pragma unroll
            for (int i = 0; i < 4; ++i) af[i] = Av[k8 * 65 + i * 16 + l15];
            #pragma unroll
            for (int j = 0; j < 2; ++j) bfr[j] = Bv[k8 * 129 + wn * 32 + j * 16 + l15];
            #pragma unroll
            for (int i = 0; i < 4; ++i)
                #pragma unroll
                for (int j = 0; j < 2; ++j)
                    acc[i][j] = __builtin_amdgcn_mfma_f32_16x16x32_bf16(af[i], bfr[j], acc[i][j], 0, 0, 0);
        }
    }

    if (z == 2) {   // V epilogue -> global bf16
        #pragma unroll
        for (int i = 0; i < 4; ++i)
            #pragma unroll
            for (int j = 0; j < 2; ++j) {
                int c = col0 + wn * 32 + j * 16 + l15;
                float bv_ = bias[c];
                #pragma unroll
                for (int reg = 0; reg < 4; ++reg) {
                    int r = row0 + i * 16 + quad * 4 + reg;
                    Vb[r * DMODEL + c] = f2bf(acc[i][j][reg] + bv_);
                }
            }
        return;
    }

    // ---- Q/K epilogue -> LDS tile ----
    #pragma unroll
    for (int i = 0; i < 4; ++i)
        #pragma unroll
        for (int j = 0; j < 2; ++j) {
            int c = wn * 32 + j * 16 + l15;                  // 0..127 (2 heads)
            float bv_ = bias[col0 + c];
            #pragma unroll
            for (int reg = 0; reg < 4; ++reg) {
                int r = i * 16 + quad * 4 + reg;             // 0..63
                Qt[r * 136 + c] = f2bf(acc[i][j][reg] + bv_);
            }
        }
    __syncthreads();     // all As8/Bs8 reads done; safe to alias with RFTs

    {   // stage RF -> RFTs[m][d] bf16 with SCALE folded (coalesced in m)
        int m = tid & 127, half = tid >> 7;
        #pragma unroll
        for (int j = 0; j < 32; ++j) {
            int d = half * 32 + j;
            RFTs[m * 72 + d] = f2bf(SCALE * RF[d * M + m]);
        }
    }
    if (isK && tid < 128) {      // per (head-half, row) sumsq
        int hh = tid >> 6, row = tid & 63;
        float s = 0.f;
        #pragma unroll
        for (int d = 0; d < DH; ++d) {
            float v = bf2f(Qt[row * 136 + hh * 64 + d]);
            s += v * v;
        }
        ssq[tid] = s;
    }
    __syncthreads();

    // ---- primes MFMA: per wave (head-half hh, m-half mh), 64 rows x 64 m ----
    const int hh = wave >> 1, mh = wave & 1;
    const float s2h = 0.5f * SCALE * SCALE;
    f32x4 pac[4][4];
    #pragma unroll
    for (int i = 0; i < 4; ++i)
        #pragma unroll
        for (int j = 0; j < 4; ++j) pac[i][j] = z4;
    #pragma unroll
    for (int kc = 0; kc < 2; ++kc) {
        bf16x8 af[4], bfr[4];
        #pragma unroll
        for (int i = 0; i < 4; ++i)
            af[i] = *(const bf16x8*)&Qt[(i * 16 + l15) * 136 + hh * 64 + kc * 32 + quad * 8];
        #pragma unroll
        for (int j = 0; j < 4; ++j)
            bfr[j] = *(const bf16x8*)&RFTs[(mh * 64 + j * 16 + l15) * 72 + kc * 32 + quad * 8];
        #pragma unroll
        for (int i = 0; i < 4; ++i)
            #pragma unroll
            for (int j = 0; j < 4; ++j)
                pac[i][j] = __builtin_amdgcn_mfma_f32_16x16x32_bf16(af[i], bfr[j], pac[i][j], 0, 0, 0);
    }

    ushort_t* dst = isK ? KPb : QPb;
    const int hgl = blockIdx.y * 2 + hh;
    #pragma unroll
    for (int i = 0; i < 4; ++i)
        #pragma unroll
        for (int reg = 0; reg < 4; ++reg) {
            int row = i * 16 + quad * 4 + reg;
            float off = isK ? (-s2h * ssq[hh * 64 + row]) : 0.f;
            #pragma unroll
            for (int j = 0; j < 4; ++j) {
                int m = mh * 64 + j * 16 + l15;
                float p = pac[i][j][reg] + off;
                dst[((long)hgl * L + row0 + row) * M + m] = f2bf(NCONST * (expf(p) + KEPS));
            }
        }
}

// ---------------- output GEMM (bf16 A, fp32 W inline-cast), K-chunk 64 ------
__global__ __launch_bounds__(256) void out_gemm_kernel(
    const ushort_t* __restrict__ ctxb, const float* __restrict__ Wo,
    const float* __restrict__ bo, float* __restrict__ out)
{
    __shared__ uint4 As8[8 * 33];    // [k8][row] stride 33 (padded)
    __shared__ uint4 Bs8[8 * 129];   // [k8][col] stride 129 (padded)
    const int tid  = threadIdx.x;
    const int lane = tid & 63;
    const int wn   = tid >> 6;
    const int quad = lane >> 4;
    const int l15  = lane & 15;
    const int row0 = blockIdx.x * 32;
    const int col0 = blockIdx.y * 128;

    f32x4 acc[2][2];
    const f32x4 z4 = {0.f, 0.f, 0.f, 0.f};
    acc[0][0] = z4; acc[0][1] = z4; acc[1][0] = z4; acc[1][1] = z4;

    uint4 ra, rb[4];
    auto loadA = [&](int ck) {
        int row = tid >> 3, k8 = tid & 7;    // coalesced: 8 lanes per 256B row chunk
        ra = *(const uint4*)&ctxb[(row0 + row) * DMODEL + ck * 64 + k8 * 8];
    };
    auto loadB = [&](int ck) {
        #pragma unroll
        for (int it = 0; it < 4; ++it) {
            int t = tid + it * 256;
            int col = t >> 3, k8 = t & 7;
            const float4* gp = (const float4*)&Wo[(col0 + col) * DMODEL + ck * 64 + k8 * 8];
            float4 v0 = gp[0], v1 = gp[1];
            rb[it] = make_uint4(pack2(v0.x, v0.y), pack2(v0.z, v0.w),
                                pack2(v1.x, v1.y), pack2(v1.z, v1.w));
        }
    };

    loadA(0); loadB(0);
    for (int ck = 0; ck < 8; ++ck) {
        __syncthreads();
        As8[(tid & 7) * 33 + (tid >> 3)] = ra;
        #pragma unroll
        for (int it = 0; it < 4; ++it) {
            int t = tid + it * 256;
            Bs8[(t & 7) * 129 + (t >> 3)] = rb[it];
        }
        __syncthreads();
        if (ck < 7) { loadA(ck + 1); loadB(ck + 1); }
        const bf16x8* Av = (const bf16x8*)As8;
        const bf16x8* Bv = (const bf16x8*)Bs8;
        #pragma unroll
        for (int kc = 0; kc < 2; ++kc) {
            const int k8 = kc * 4 + quad;
            bf16x8 af[2], bfr[2];
            af[0] = Av[k8 * 33 + l15];
            af[1] = Av[k8 * 33 + 16 + l15];
            #pragma unroll
            for (int j = 0; j < 2; ++j) bfr[j] = Bv[k8 * 129 + wn * 32 + j * 16 + l15];
            #pragma unroll
            for (int i = 0; i < 2; ++i)
                #pragma unroll
                for (int j = 0; j < 2; ++j)
                    acc[i][j] = __builtin_amdgcn_mfma_f32_16x16x32_bf16(af[i], bfr[j], acc[i][j], 0, 0, 0);
        }
    }
    #pragma unroll
    for (int i = 0; i < 2; ++i)
        #pragma unroll
        for (int j = 0; j < 2; ++j) {
            int c = col0 + wn * 32 + j * 16 + l15;
            float bv_ = bo[c];
            #pragma unroll
            for (int reg = 0; reg < 4; ++reg) {
                int r = row0 + i * 16 + quad * 4 + reg;
                out[r * DMODEL + c] = acc[i][j][reg] + bv_;
            }
        }
}

// ------- chunk sums via MFMA: S[m][d] = K'^T V, z[m] via ones-row -----------
__global__ __launch_bounds__(256) void chunksum_mfma_kernel(
    const ushort_t* __restrict__ KPb, const ushort_t* __restrict__ Vb,
    ushort_t* __restrict__ SSb, float* __restrict__ SSz)
{
    __shared__ ushort_t Kt[128 * 72];   // K'^T [m][t]
    __shared__ ushort_t Vt[80 * 72];    // V^T [d][t]; row 64 = ones; 65..79 zero
    const int tid = threadIdx.x;
    const int c = blockIdx.x, h = blockIdx.y;
    const int lane = tid & 63;
    const int wave = tid >> 6;
    const int quad = lane >> 4, l15 = lane & 15;
    const int t = lane, g = wave;

    {   // transpose-stage K' (64x128) and V (64x64); lanes along t -> conflict-free
        const ushort_t* kr = &KPb[((long)(h * L) + c * CT + t) * M];
        #pragma unroll
        for (int it = 0; it < 4; ++it) {
            int mo = it * 4 + g;
            uint4 u = *(const uint4*)&kr[mo * 8];
            ushort_t e[8] = {(ushort_t)(u.x & 0xffff), (ushort_t)(u.x >> 16),
                             (ushort_t)(u.y & 0xffff), (ushort_t)(u.y >> 16),
                             (ushort_t)(u.z & 0xffff), (ushort_t)(u.z >> 16),
                             (ushort_t)(u.w & 0xffff), (ushort_t)(u.w >> 16)};
            #pragma unroll
            for (int j = 0; j < 8; ++j) Kt[(mo * 8 + j) * 72 + t] = e[j];
        }
        const ushort_t* vr = &Vb[(c * CT + t) * DMODEL + h * DH];
        #pragma unroll
        for (int it = 0; it < 2; ++it) {
            int dd = it * 4 + g;
            uint4 u = *(const uint4*)&vr[dd * 8];
            ushort_t e[8] = {(ushort_t)(u.x & 0xffff), (ushort_t)(u.x >> 16),
                             (ushort_t)(u.y & 0xffff), (ushort_t)(u.y >> 16),
                             (ushort_t)(u.z & 0xffff), (ushort_t)(u.z >> 16),
                             (ushort_t)(u.w & 0xffff), (ushort_t)(u.w >> 16)};
            #pragma unroll
            for (int j = 0; j < 8; ++j) Vt[(dd * 8 + j) * 72 + t] = e[j];
        }
        if (g == 0) Vt[64 * 72 + t] = 0x3F80;     // bf16 1.0
        if (g == 1) {
            #pragma unroll
            for (int r = 65; r < 80; ++r) Vt[r * 72 + t] = 0;
        }
    }
    __syncthreads();

    f32x4 acc[2][5];
    const f32x4 z4 = {0.f, 0.f, 0.f, 0.f};
    #pragma unroll
    for (int i = 0; i < 2; ++i)
        #pragma unroll
        for (int j = 0; j < 5; ++j) acc[i][j] = z4;
    #pragma unroll
    for (int kt = 0; kt < 2; ++kt) {
        bf16x8 af[2], bfr[5];
        #pragma unroll
        for (int i = 0; i < 2; ++i)
            af[i] = *(const bf16x8*)&Kt[(wave * 32 + i * 16 + l15) * 72 + kt * 32 + quad * 8];
        #pragma unroll
        for (int j = 0; j < 5; ++j)
            bfr[j] = *(const bf16x8*)&Vt[(j * 16 + l15) * 72 + kt * 32 + quad * 8];
        #pragma unroll
        for (int i = 0; i < 2; ++i)
            #pragma unroll
            for (int j = 0; j < 5; ++j)
                acc[i][j] = __builtin_amdgcn_mfma_f32_16x16x32_bf16(af[i], bfr[j], acc[i][j], 0, 0, 0);
    }
    ushort_t* outS = SSb + (long)(h * NC + c) * 8192;
    #pragma unroll
    for (int i = 0; i < 2; ++i)
        #pragma unroll
        for (int reg = 0; reg < 4; ++reg) {
            int m = wave * 32 + i * 16 + quad * 4 + reg;
            #pragma unroll
            for (int j = 0; j < 4; ++j)
                outS[m * 64 + j * 16 + l15] = f2bf(acc[i][j][reg]);
            if (l15 == 0) SSz[(h * NC + c) * M + m] = acc[i][4][reg];
        }
}

// ------- in-place exclusive prefix over chunks (batched loads) --------------
__global__ __launch_bounds__(256) void prefix_kernel(
    ushort_t* __restrict__ SSb, float* __restrict__ SSz)
{
    const int h = blockIdx.y;
    if (blockIdx.x == 32) {
        const int m = threadIdx.x;
        if (m < M) {
            float v[NC];
            #pragma unroll
            for (int c = 0; c < NC; ++c) v[c] = SSz[(h * NC + c) * M + m];
            float run = 0.f;
            #pragma unroll
            for (int c = 0; c < NC; ++c) {
                SSz[(h * NC + c) * M + m] = run;
                run += v[c];
            }
        }
        return;
    }
    const int idx = blockIdx.x * 256 + threadIdx.x;   // < 8192
    ushort_t v[NC];
    #pragma unroll
    for (int c = 0; c < NC; ++c) v[c] = SSb[(long)(h * NC + c) * 8192 + idx];
    float run = 0.f;
    #pragma unroll
    for (int c = 0; c < NC; ++c) {
        SSb[(long)(h * NC + c) * 8192 + idx] = f2bf(run);
        run += bf2f(v[c]);
    }
}

// ---------------- per-chunk causal kernel attention (MFMA) ------------------
// den = [Am|Q'] @ [ones;z] = output column 64 of the phase-2 MFMA.
__global__ __launch_bounds__(512) void attn_kernel(
    const ushort_t* __restrict__ QPb, const ushort_t* __restrict__ KPb,
    const ushort_t* __restrict__ Vb, const ushort_t* __restrict__ SSb,
    const float* __restrict__ SSz, ushort_t* __restrict__ ctxb)
{
    __shared__ ushort_t Qp[64 * 136];   // stride 136 bf16
    __shared__ ushort_t Kp[64 * 136];
    __shared__ ushort_t St[80 * 136];   // S^T [d][m]; row 64 = z
    __shared__ ushort_t Vt[80 * 72];    // V^T [d][t]; row 64 = ones
    __shared__ ushort_t Am[64 * 72];    // masked scores [row][col]
    __shared__ float den[CT];
    const int tid = threadIdx.x;
    const int c = blockIdx.x, h = blockIdx.y;
    const int lane = tid & 63;
    const int wave = tid >> 6;
    const int i  = wave & 3;            // rows tile (16 rows)
    const int nh = wave >> 2;           // cols half (32 cols)
    const int quad = lane >> 4;
    const int l15  = lane & 15;

    // ---- stage ----
    for (int t = tid; t < 2048; t += 512) {          // Qp/Kp
        int mat = t >> 10, r = (t >> 4) & 63, c8 = t & 15;
        const ushort_t* src = mat ? KPb : QPb;
        uint4 u = *(const uint4*)&src[((long)(h * L) + c * CT + r) * M + c8 * 8];
        ushort_t* dst = mat ? Kp : Qp;
        *(uint4*)&dst[r * 136 + c8 * 8] = u;
    }
    {   // Vt: transpose V 64x64 bf16
        int t = tid & 63, dg = tid >> 6;
        uint4 u = *(const uint4*)&Vb[(c * CT + t) * DMODEL + h * DH + dg * 8];
        ushort_t e[8] = {(ushort_t)(u.x & 0xffff), (ushort_t)(u.x >> 16),
                         (ushort_t)(u.y & 0xffff), (ushort_t)(u.y >> 16),
                         (ushort_t)(u.z & 0xffff), (ushort_t)(u.z >> 16),
                         (ushort_t)(u.w & 0xffff), (ushort_t)(u.w >> 16)};
        #pragma unroll
        for (int j = 0; j < 8; ++j) Vt[(dg * 8 + j) * 72 + t] = e[j];
    }
    {   // St[d][m] from S[m][d] (transpose-scatter, lanes along m -> free)
        const ushort_t* ssb = SSb + (long)(h * NC + c) * 8192;
        int m = tid & 127, dg = tid >> 7;    // dg 0..3
        #pragma unroll
        for (int it = 0; it < 2; ++it) {
            int dd = it * 4 + dg;            // d-octet 0..7
            uint4 u = *(const uint4*)&ssb[m * 64 + dd * 8];
            ushort_t e[8] = {(ushort_t)(u.x & 0xffff), (ushort_t)(u.x >> 16),
                             (ushort_t)(u.y & 0xffff), (ushort_t)(u.y >> 16),
                             (ushort_t)(u.z & 0xffff), (ushort_t)(u.z >> 16),
                             (ushort_t)(u.w & 0xffff), (ushort_t)(u.w >> 16)};
            #pragma unroll
            for (int j = 0; j < 8; ++j) St[(dd * 8 + j) * 136 + m] = e[j];
        }
    }
    if (tid < 128) St[64 * 136 + tid] = f2bf(SSz[(h * NC + c) * M + tid]);  // z row
    if (tid >= 128 && tid < 192) Vt[64 * 72 + (tid - 128)] = 0x3F80;        // ones
    for (int t = tid; t < 15 * 136; t += 512) St[65 * 136 + t] = 0;         // pad
    for (int t = tid; t < 15 * 72; t += 512)  Vt[65 * 72 + t] = 0;
    __syncthreads();

    // ---- phase 1: scores ----
    f32x4 acc1[2];
    const f32x4 z4 = {0.f, 0.f, 0.f, 0.f};
    acc1[0] = z4; acc1[1] = z4;
    #pragma unroll
    for (int kt = 0; kt < 4; ++kt) {
        bf16x8 af = *(const bf16x8*)&Qp[(i * 16 + l15) * 136 + kt * 32 + quad * 8];
        #pragma unroll
        for (int jt = 0; jt < 2; ++jt) {
            bf16x8 bf = *(const bf16x8*)&Kp[(nh * 32 + jt * 16 + l15) * 136 + kt * 32 + quad * 8];
            acc1[jt] = __builtin_amdgcn_mfma_f32_16x16x32_bf16(af, bf, acc1[jt], 0, 0, 0);
        }
    }
    #pragma unroll
    for (int jt = 0; jt < 2; ++jt) {
        int col = nh * 32 + jt * 16 + l15;
        #pragma unroll
        for (int reg = 0; reg < 4; ++reg) {
            int row = i * 16 + quad * 4 + reg;
            Am[row * 72 + col] = f2bf((col <= row) ? acc1[jt][reg] : 0.f);
        }
    }
    __syncthreads();

    // ---- phase 2: N = [Am|Q'] @ [V;S], den = column 64 ----
    f32x4 acc2[2], acc3;
    acc2[0] = z4; acc2[1] = z4; acc3 = z4;
    #pragma unroll
    for (int kt = 0; kt < 6; ++kt) {
        bf16x8 af = (kt < 2)
            ? *(const bf16x8*)&Am[(i * 16 + l15) * 72 + kt * 32 + quad * 8]
            : *(const bf16x8*)&Qp[(i * 16 + l15) * 136 + (kt - 2) * 32 + quad * 8];
        #pragma unroll
        for (int jt = 0; jt < 2; ++jt) {
            int n = nh * 32 + jt * 16 + l15;
            bf16x8 bf = (kt < 2)
                ? *(const bf16x8*)&Vt[n * 72 + kt * 32 + quad * 8]
                : *(const bf16x8*)&St[n * 136 + (kt - 2) * 32 + quad * 8];
            acc2[jt] = __builtin_amdgcn_mfma_f32_16x16x32_bf16(af, bf, acc2[jt], 0, 0, 0);
        }
        if (nh == 0) {
            bf16x8 bz = (kt < 2)
                ? *(const bf16x8*)&Vt[(64 + l15) * 72 + kt * 32 + quad * 8]
                : *(const bf16x8*)&St[(64 + l15) * 136 + (kt - 2) * 32 + quad * 8];
            acc3 = __builtin_amdgcn_mfma_f32_16x16x32_bf16(af, bz, acc3, 0, 0, 0);
        }
    }
    if (nh == 0 && l15 == 0) {
        #pragma unroll
        for (int reg = 0; reg < 4; ++reg)
            den[i * 16 + quad * 4 + reg] = acc3[reg];
    }
    __syncthreads();
    #pragma unroll
    for (int jt = 0; jt < 2; ++jt) {
        int d = nh * 32 + jt * 16 + l15;
        #pragma unroll
        for (int reg = 0; reg < 4; ++reg) {
            int row = i * 16 + quad * 4 + reg;
            ctxb[(c * CT + row) * DMODEL + h * DH + d] = f2bf(acc2[jt][reg] / (den[row] + DEPS));
        }
    }
}

extern "C" void kernel_launch(void* const* d_in, const int* in_sizes, int n_in,
                              void* d_out, int out_size, void* d_ws, size_t ws_size,
                              hipStream_t stream)
{
    const float* query = (const float*)d_in[0];
    const float* key_  = (const float*)d_in[1];
    const float* value = (const float*)d_in[2];
    const float* Wq = (const float*)d_in[3];
    const float* bq = (const float*)d_in[4];
    const float* Wk = (const float*)d_in[5];
    const float* bk = (const float*)d_in[6];
    const float* Wv = (const float*)d_in[7];
    const float* bv = (const float*)d_in[8];
    const float* Wo = (const float*)d_in[9];
    const float* bo = (const float*)d_in[10];
    const float* RF = (const float*)d_in[11];

    float* ws = (float*)d_ws;
    ushort_t* Vb   = (ushort_t*)(ws + OFF_VB);
    ushort_t* QPb  = (ushort_t*)(ws + OFF_QPB);
    ushort_t* KPb  = (ushort_t*)(ws + OFF_KPB);
    ushort_t* SSb  = (ushort_t*)(ws + OFF_SSB);
    float* SSz     = ws + OFF_SSZ;
    ushort_t* CTXB = (ushort_t*)(ws + OFF_CTX);

    qkvp_kernel<<<dim3(32, 4, 3), 256, 0, stream>>>(query, key_, value,
                                                    Wq, bq, Wk, bk, Wv, bv, RF,
                                                    Vb, QPb, KPb);
    chunksum_mfma_kernel<<<dim3(NC, 8), 256, 0, stream>>>(KPb, Vb, SSb, SSz);
    prefix_kernel<<<dim3(33, 8), 256, 0, stream>>>(SSb, SSz);
    attn_kernel<<<dim3(NC, 8), 512, 0, stream>>>(QPb, KPb, Vb, SSb, SSz, CTXB);
    out_gemm_kernel<<<dim3(64, 4), 256, 0, stream>>>(CTXB, Wo, bo, (float*)d_out);
}